// Round 16
// baseline (244.789 us; speedup 1.0000x reference)
//
#include <hip/hip_runtime.h>

namespace {

constexpr int GX = 400, GY = 400;
constexpr int P = 32;
constexpr int K = 60000;
constexpr int MCAP = 128;
constexpr int NB = 4;
constexpr int NVOX = NB * GX * GY;   // 640000 < 2^20
constexpr int SCAN_CHUNK = 1024;
constexpr int NBLK = (NVOX + 1 + SCAN_CHUNK - 1) / SCAN_CHUNK;  // 626
constexpr int OCC_PAD = NBLK * SCAN_CHUNK;                      // 641024

// bijective pairing: u = (flat*A) mod 2^20; bucket = u>>11 (512); j = u&2047.
constexpr unsigned A20 = 0x779B1u;
constexpr unsigned mulinv20(unsigned a) {
  unsigned x = a;
  for (int i = 0; i < 6; ++i) x *= 2u - a * x;
  return x & 0xFFFFFu;
}
constexpr unsigned AINV20 = mulinv20(A20);
static_assert(((A20 * AINV20) & 0xFFFFFu) == 1u, "bad inverse");

constexpr int NBUK3 = 512;               // buckets
constexpr int NPART = 8;                 // sub-arenas per bucket (blockIdx&7)
constexpr int CAPS = 640;                // per-sub-arena cap (mean 488, +6.9 sigma)
constexpr int CAP3 = NPART * CAPS;       // 5120 per bucket (grouped region)
constexpr int JH = 2048;                 // j-space per bucket

constexpr float XMINf = -20.f, YMINf = -20.f, ZMINf = -2.f;
constexpr float XMAXf =  20.f, YMAXf =  20.f, ZMAXf =  3.f;

constexpr int OUT_CNT = K * P * 4;
constexpr int OUT_COR = OUT_CNT + K;

typedef float floatx2 __attribute__((ext_vector_type(2)));

// DO NOT TOUCH: this exact f32 expression matches the np reference's binning.
__device__ __forceinline__ int bin_of(float v) {
  return (int)((v + 20.0f) * 10.0f);
}

__device__ __forceinline__ bool point_voxel(const float* __restrict__ pt, int& flat) {
  float x = pt[1], y = pt[2], z = pt[3];
  bool m = (x >= XMINf) & (x < XMAXf) & (y >= YMINf) & (y < YMAXf)
         & (z >= ZMINf) & (z < ZMAXf);
  if (!m) return false;
  int bi = (int)pt[0];
  int xi = min(max(bin_of(x), 0), GX - 1);
  int yi = min(max(bin_of(y), 0), GY - 1);
  flat = bi * (GX * GY) + xi * GY + yi;
  return true;
}

__device__ __forceinline__ unsigned bf16rne(float f) {
  unsigned u = __float_as_uint(f);
  return ((u + 0x7fffu + ((u >> 16) & 1u)) >> 16) & 0xffffu;
}
__device__ __forceinline__ float bf16dq(unsigned h) {
  return __uint_as_float(h << 16);
}

// ---- pass 1: NO-LDS direct scatter into per-(bucket, blockIdx&7) arenas --
// 4096 sub-arenas; cursors L2-hot (4096 ints); each part's record lines are
// written only by same-part blocks (round-robin blockIdx -> same XCD L2,
// 3.8 MB/XCD footprint) so 64B lines fill before eviction. Zero barriers.
__global__ void __launch_bounds__(256) k_scatter(
    const float* __restrict__ pts, int n, int* __restrict__ occ,
    int* __restrict__ bcur2, unsigned* __restrict__ akey,
    uint2* __restrict__ afeat) {
  int part = blockIdx.x & (NPART - 1);
  int base = (blockIdx.x * 256 + threadIdx.x) * 4;
  #pragma unroll
  for (int j = 0; j < 4; ++j) {
    int i = base + j;
    if (i >= n) break;
    const float* pp = pts + (size_t)i * 5;
    int flat;
    if (point_voxel(pp, flat)) {
      occ[flat] = 1;                               // benign race
      unsigned u = ((unsigned)flat * A20) & 0xFFFFFu;
      int b = (int)(u >> 11);
      unsigned key = ((u & 0x7FFu) << 21) | (unsigned)i;
      int pos = atomicAdd(&bcur2[b * NPART + part], 1);
      if (pos < CAPS) {
        size_t a = (size_t)(b * NPART + part) * CAPS + pos;
        akey[a] = key;
        afeat[a] = make_uint2(bf16rne(pp[1]) | (bf16rne(pp[2]) << 16),
                              bf16rne(pp[3]) | (bf16rne(pp[4]) << 16));
      }
    }
  }
}

// ---- pass 2a/2b/2c: occupancy scan chain (proven) ------------------------
__global__ void k_bsum(const int* __restrict__ occ, int* __restrict__ bsum) {
  __shared__ int wsums[4];
  int t = threadIdx.x, wid = t >> 6, lane = t & 63;
  int base = blockIdx.x * SCAN_CHUNK;
  int4 v = ((const int4*)(occ + base))[t];
  int s = v.x + v.y + v.z + v.w;
  for (int o = 32; o > 0; o >>= 1) s += __shfl_xor(s, o, 64);
  if (lane == 0) wsums[wid] = s;
  __syncthreads();
  if (t == 0) bsum[blockIdx.x] = wsums[0] + wsums[1] + wsums[2] + wsums[3];
}

__global__ void k_scanb(int* __restrict__ bsum) {
  __shared__ int lds[1024];
  int t = threadIdx.x;
  int v = (t < NBLK) ? bsum[t] : 0;
  lds[t] = v;
  __syncthreads();
  for (int o = 1; o < 1024; o <<= 1) {
    int add = (t >= o) ? lds[t - o] : 0;
    __syncthreads();
    lds[t] += add;
    __syncthreads();
  }
  if (t < NBLK) bsum[t] = lds[t] - v;
  if (t == NBLK - 1) bsum[NBLK] = lds[t];         // num_unique
}

__global__ void k_rank(int* __restrict__ occ, const int* __restrict__ bsum,
                       int* __restrict__ uniq) {
  __shared__ int wsums[4];
  int t = threadIdx.x, wid = t >> 6, lane = t & 63;
  int base = blockIdx.x * SCAN_CHUNK;
  int4 v = ((const int4*)(occ + base))[t];
  int tsum = v.x + v.y + v.z + v.w;
  int sc = tsum;
  for (int o = 1; o < 64; o <<= 1) {
    int u = __shfl_up(sc, o, 64);
    if (lane >= o) sc += u;
  }
  if (lane == 63) wsums[wid] = sc;
  __syncthreads();
  int woff = 0;
  for (int w = 0; w < wid; ++w) woff += wsums[w];
  int p = bsum[blockIdx.x] + woff + (sc - tsum);
  int e0 = base + t * 4;
  int4 r;
  r.x = p; if (v.x) { if (p < K) uniq[p] = e0 + 0; ++p; }
  r.y = p; if (v.y) { if (p < K) uniq[p] = e0 + 1; ++p; }
  r.z = p; if (v.z) { if (p < K) uniq[p] = e0 + 2; ++p; }
  r.w = p; if (v.w) { if (p < K) uniq[p] = e0 + 3; ++p; }
  ((int4*)(occ + base))[t] = r;
}

// ---- pass 3: per-bucket grouping. Stage the 8 segs (they ARE the bucket's
// contiguous 5120-slot region), hist+scan 2048 j-bins, rewrite in place
// grouped by voxel; gpos = seg*CAPS+pos (u16) for feature lookup -----------
__global__ void __launch_bounds__(256) k_build2(
    unsigned* __restrict__ akey, unsigned short* __restrict__ gpos,
    const int* __restrict__ bcur2, const int* __restrict__ rank,
    const int* __restrict__ nuq_p, int* __restrict__ voxoff,
    int* __restrict__ vcnt) {
  __shared__ unsigned st[CAP3];                  // 20 KB
  __shared__ int hist[JH], scn[JH], cur[JH];     // 24 KB
  __shared__ int ps[256];
  __shared__ int segb[NPART + 1];
  int b = blockIdx.x, t = threadIdx.x;
  for (int j = t; j < JH; j += 256) hist[j] = 0;
  if (t == 0) {
    int run = 0;
    for (int s = 0; s < NPART; ++s) {
      segb[s] = run;
      run += min(bcur2[b * NPART + s], CAPS);
    }
    segb[NPART] = run;
  }
  __syncthreads();
  unsigned* keys = akey + (size_t)b * CAP3;
  // stage + histogram (reads complete before any grouped overwrite)
  for (int s = 0; s < NPART; ++s) {
    int c = segb[s + 1] - segb[s];
    const unsigned* seg = akey + ((size_t)b * NPART + s) * CAPS;
    for (int i = t; i < c; i += 256) {
      unsigned kk = seg[i];
      st[segb[s] + i] = kk;
      atomicAdd(&hist[kk >> 21], 1);
    }
  }
  __syncthreads();
  int h[8]; int local = 0;
  #pragma unroll
  for (int u = 0; u < 8; ++u) { h[u] = hist[8 * t + u]; local += h[u]; }
  ps[t] = local;
  __syncthreads();
  for (int o = 1; o < 256; o <<= 1) {
    int add = (t >= o) ? ps[t - o] : 0;
    __syncthreads();
    ps[t] += add;
    __syncthreads();
  }
  int run = ps[t] - local;
  #pragma unroll
  for (int u = 0; u < 8; ++u) { scn[8 * t + u] = run; cur[8 * t + u] = run; run += h[u]; }
  __syncthreads();
  int tot = segb[NPART];
  int cbase = b * CAP3;
  for (int e = t; e < tot; e += 256) {           // grouped in-place rewrite
    unsigned kk = st[e];
    int s = 0;
    #pragma unroll
    for (int q = 1; q < NPART; ++q) s += (e >= segb[q]);
    int srcoff = s * CAPS + (e - segb[s]);
    int slot = atomicAdd(&cur[kk >> 21], 1);
    keys[slot] = kk & 0x1FFFFFu;                 // point idx
    gpos[cbase + slot] = (unsigned short)srcoff;
  }
  int nq = min(nuq_p[0], K);
  for (int j = t; j < JH; j += 256) {
    if (hist[j] > 0) {
      unsigned u = ((unsigned)b << 11) | (unsigned)j;
      int flat = (int)((u * AINV20) & 0xFFFFFu);
      int k = rank[flat];
      if (k >= 0 && k < nq) {
        voxoff[k] = cbase + scn[j];
        vcnt[k] = hist[j];
      }
    }
  }
}

// ---- pass 4: per-voxel sort + feature fetch + output (zero LDS) ----------
__global__ void __launch_bounds__(256) k_final_g(
    const unsigned* __restrict__ akey, const unsigned short* __restrict__ gpos,
    const uint2* __restrict__ afeat, const int* __restrict__ uniq,
    const int* __restrict__ voxoff, const int* __restrict__ vcnt,
    const int* __restrict__ nuq_p, float* __restrict__ out) {
  int wid = threadIdx.x >> 6, lane = threadIdx.x & 63;
  int k = blockIdx.x * 4 + wid;
  if (k >= K) return;
  int nq = min(nuq_p[0], K);
  const unsigned UMAX = 0xffffffffu;
  int s = lane >> 1, hh = lane & 1;

  int c_tot = 0, c_out = 0, off = 0;
  if (k < nq) {
    off = voxoff[k];
    int c = vcnt[k];
    c_tot = min(c, MCAP);
    c_out = min(c, P);
  }

  unsigned pos_s = 0u;
  if (c_tot > 0) {
    if (c_tot <= 64) {
      unsigned key = (lane < c_tot) ? akey[off + lane] : UMAX;
      unsigned pos = (lane < c_tot) ? (unsigned)gpos[off + lane] : 0u;
      for (int kk = 2; kk <= 64; kk <<= 1) {
        for (int d = kk >> 1; d >= 1; d >>= 1) {
          unsigned pk = __shfl_xor(key, d, 64);
          unsigned pq = __shfl_xor(pos, d, 64);
          bool tmin = ((lane & d) == 0) == ((lane & kk) == 0);
          bool sw = tmin ? (pk < key) : (pk > key);
          if (sw) { key = pk; pos = pq; }
        }
      }
      pos_s = __shfl(pos, s, 64);
    } else {
      unsigned k0 = (lane < c_tot) ? akey[off + lane] : UMAX;
      unsigned p0 = (lane < c_tot) ? (unsigned)gpos[off + lane] : 0u;
      unsigned k1 = (lane + 64 < c_tot) ? akey[off + 64 + lane] : UMAX;
      unsigned p1 = (lane + 64 < c_tot) ? (unsigned)gpos[off + 64 + lane] : 0u;
      #pragma unroll
      for (int ph = 1; ph <= 7; ++ph) {
        int kk = 1 << ph;
        bool up = ((lane & (kk >> 1)) == 0);
        #pragma unroll
        for (int d = kk >> 1; d >= 2; d >>= 1) {
          int dl = d >> 1;
          unsigned q0 = __shfl_xor(k0, dl, 64), r0 = __shfl_xor(p0, dl, 64);
          unsigned q1 = __shfl_xor(k1, dl, 64), r1 = __shfl_xor(p1, dl, 64);
          bool low = ((lane & dl) == 0);
          if (low == up) {
            if (q0 < k0) { k0 = q0; p0 = r0; }
            if (q1 < k1) { k1 = q1; p1 = r1; }
          } else {
            if (q0 > k0) { k0 = q0; p0 = r0; }
            if (q1 > k1) { k1 = q1; p1 = r1; }
          }
        }
        bool sw = up ? (k1 < k0) : (k1 > k0);
        if (sw) {
          unsigned tk = k0; k0 = k1; k1 = tk;
          unsigned tp = p0; p0 = p1; p1 = tp;
        }
      }
      unsigned a0 = __shfl(p0, s >> 1, 64);
      unsigned a1 = __shfl(p1, s >> 1, 64);
      pos_s = (s & 1) ? a1 : a0;
    }
  }

  uint2 fv = make_uint2(0u, 0u);
  if (s < c_out) {
    int b = off / CAP3;
    fv = afeat[(size_t)b * CAP3 + pos_s];        // b*5120 + seg*640 + pos
  }
  float va, vb;
  if (hh == 0) { va = bf16dq(fv.x & 0xffffu); vb = bf16dq(fv.x >> 16); }
  else         { va = bf16dq(fv.y & 0xffffu); vb = bf16dq(fv.y >> 16); }
  floatx2 val = {va, vb};
  __builtin_nontemporal_store(val, (floatx2*)(out + (size_t)k * (P * 4)) + lane);

  if (lane == 0) {
    out[OUT_CNT + k] = (float)c_out;
    int f = (k < nq) ? uniq[k] : NVOX;
    int cb = f / (GX * GY), rem = f % (GX * GY);
    out[OUT_COR + (size_t)k * 3 + 0] = (float)cb;
    out[OUT_COR + (size_t)k * 3 + 1] = (float)(rem / GY);
    out[OUT_COR + (size_t)k * 3 + 2] = (float)(rem % GY);
  }
}

// ======== fallback path C (proven R6): candidates voxel-major in d_out ====
__global__ void k_mark(const float* __restrict__ pts, int n,
                       int* __restrict__ occ, int* __restrict__ pflat) {
  int i = blockIdx.x * blockDim.x + threadIdx.x;
  if (i >= n) return;
  int flat = -1;
  if (point_voxel(pts + (size_t)i * 5, flat)) occ[flat] = 1;
  if (pflat) pflat[i] = flat;
}

__global__ void k_append(const int* __restrict__ pflat, int n,
                         const int* __restrict__ rank, int* __restrict__ cnt,
                         unsigned* __restrict__ vox) {
  int i = blockIdx.x * blockDim.x + threadIdx.x;
  if (i >= n) return;
  int f = pflat[i];
  if (f < 0) return;
  int v = rank[f];
  if (v >= K) return;
  int pos = atomicAdd(&cnt[v], 1);
  if (pos < MCAP) vox[(size_t)v * MCAP + pos] = (unsigned)i;
}

__global__ void k_append_fb(const float* __restrict__ pts, int n,
                            const int* __restrict__ rank, int* __restrict__ cnt,
                            unsigned* __restrict__ vox) {
  int i = blockIdx.x * blockDim.x + threadIdx.x;
  if (i >= n) return;
  int flat;
  if (!point_voxel(pts + (size_t)i * 5, flat)) return;
  int v = rank[flat];
  if (v >= K) return;
  int pos = atomicAdd(&cnt[v], 1);
  if (pos < MCAP) vox[(size_t)v * MCAP + pos] = (unsigned)i;
}

__global__ void __launch_bounds__(256) k_final_d(
    const float* __restrict__ pts, const int* __restrict__ uniq,
    const int* __restrict__ cnt, const int* __restrict__ nuq_p,
    float* __restrict__ out) {
  int wid = threadIdx.x >> 6, lane = threadIdx.x & 63;
  int k = blockIdx.x * 4 + wid;
  if (k >= K) return;
  int nuq = min(nuq_p[0], K);
  int c_tot = 0, c_out = 0;
  if (k < nuq) {
    int c = cnt[k];
    c_tot = min(c, MCAP);
    c_out = min(c, P);
  }
  const unsigned UMAX = 0xffffffffu;
  const unsigned* row = (const unsigned*)out + (size_t)k * MCAP;
  uint2 q = ((const uint2*)row)[lane];
  unsigned v0 = (2 * lane     < c_tot) ? q.x : UMAX;
  unsigned v1 = (2 * lane + 1 < c_tot) ? q.y : UMAX;
  #pragma unroll
  for (int ph = 1; ph <= 7; ++ph) {
    int kk = 1 << ph;
    bool up = ((lane & (kk >> 1)) == 0);
    #pragma unroll
    for (int d = kk >> 1; d >= 2; d >>= 1) {
      int dl = d >> 1;
      unsigned p0 = __shfl_xor(v0, dl, 64);
      unsigned p1 = __shfl_xor(v1, dl, 64);
      bool low = ((lane & dl) == 0);
      if (low == up) { v0 = min(v0, p0); v1 = min(v1, p1); }
      else           { v0 = max(v0, p0); v1 = max(v1, p1); }
    }
    unsigned lo = min(v0, v1), hi = max(v0, v1);
    v0 = up ? lo : hi;
    v1 = up ? hi : lo;
  }
  int mys = lane >> 1, h = lane & 1;
  unsigned a0 = __shfl(v0, mys >> 1, 64);
  unsigned a1 = __shfl(v1, mys >> 1, 64);
  unsigned myidx = (mys & 1) ? a1 : a0;
  float a = 0.f, b = 0.f;
  if (mys < c_out) {
    const float* pp = pts + (size_t)myidx * 5;
    a = pp[1 + 2 * h];
    b = pp[2 + 2 * h];
  }
  float2* vout = (float2*)(out + (size_t)k * (P * 4));
  vout[lane] = make_float2(a, b);
  if (lane == 0) {
    out[OUT_CNT + k] = (float)c_out;
    int f = (k < nuq) ? uniq[k] : NVOX;
    int cb = f / (GX * GY), rem = f % (GX * GY);
    out[OUT_COR + (size_t)k * 3 + 0] = (float)cb;
    out[OUT_COR + (size_t)k * 3 + 1] = (float)(rem / GY);
    out[OUT_COR + (size_t)k * 3 + 2] = (float)(rem % GY);
  }
}

}  // namespace

extern "C" void kernel_launch(void* const* d_in, const int* in_sizes, int n_in,
                              void* d_out, int out_size, void* d_ws, size_t ws_size,
                              hipStream_t stream) {
  const float* pts = (const float*)d_in[0];
  int n = in_sizes[0] / 5;
  float* out = (float*)d_out;
  int nb_pts = (n + 255) / 256;

  // ---- path A layout (ints) ----
  size_t o_occ   = 0;                                 // OCC_PAD (becomes rank)
  size_t o_bsum  = o_occ + OCC_PAD;                   // NBLK+1
  size_t o_uniq  = o_bsum + NBLK + 1;                 // K
  size_t o_voff  = o_uniq + K;                        // K
  size_t o_vcnt  = o_voff + K;                        // K
  size_t o_bcur  = o_vcnt + K;                        // NBUK3*NPART
  size_t o_akey  = (o_bcur + NBUK3 * NPART + 3) & ~(size_t)3;  // NBUK3*CAP3
  size_t o_afeat = o_akey + (size_t)NBUK3 * CAP3;     // NBUK3*CAP3 uint2
  size_t o_gpos  = o_afeat + (size_t)NBUK3 * CAP3 * 2;// NBUK3*CAP3 u16
  size_t totA    = o_gpos + ((size_t)NBUK3 * CAP3 + 1) / 2;

  if (ws_size >= totA * sizeof(int) && n <= (1 << 21)) {
    int* occ   = (int*)d_ws + o_occ;
    int* bsum  = (int*)d_ws + o_bsum;
    int* uniq  = (int*)d_ws + o_uniq;
    int* voff  = (int*)d_ws + o_voff;
    int* vcnt  = (int*)d_ws + o_vcnt;
    int* bcur2 = (int*)d_ws + o_bcur;
    unsigned* akey = (unsigned*)((int*)d_ws + o_akey);
    uint2* afeat   = (uint2*)((int*)d_ws + o_afeat);
    unsigned short* gpos = (unsigned short*)((int*)d_ws + o_gpos);
    const int* nuq_p = bsum + NBLK;

    hipMemsetAsync(occ, 0, (size_t)OCC_PAD * sizeof(int), stream);
    hipMemsetAsync(bcur2, 0, (size_t)NBUK3 * NPART * sizeof(int), stream);
    int nb_sc = (n + 1023) / 1024;                   // 4 pts/thread
    k_scatter<<<nb_sc, 256, 0, stream>>>(pts, n, occ, bcur2, akey, afeat);
    k_bsum  <<<NBLK, 256, 0, stream>>>(occ, bsum);
    k_scanb <<<1, 1024, 0, stream>>>(bsum);
    k_rank  <<<NBLK, 256, 0, stream>>>(occ, bsum, uniq);
    k_build2<<<NBUK3, 256, 0, stream>>>(akey, gpos, bcur2, occ, nuq_p, voff, vcnt);
    k_final_g<<<(K + 3) / 4, 256, 0, stream>>>(akey, gpos, afeat, uniq, voff, vcnt, nuq_p, out);
  } else {
    // ---- path C (R6, proven): candidates voxel-major in d_out ----
    int* occ  = (int*)d_ws;
    int* bsum = occ + OCC_PAD;
    int* uniq = bsum + (NBLK + 1);
    int* cnt  = uniq + K;
    size_t base_ints = (size_t)OCC_PAD + (NBLK + 1) + K + K;
    base_ints = (base_ints + 3) & ~(size_t)3;
    int* pflat = (int*)d_ws + base_ints;
    bool use_pflat = ws_size >= (base_ints + (size_t)n) * sizeof(int);

    hipMemsetAsync(occ, 0, (size_t)OCC_PAD * sizeof(int), stream);
    hipMemsetAsync(cnt, 0, (size_t)K * sizeof(int), stream);
    k_mark  <<<nb_pts, 256, 0, stream>>>(pts, n, occ, use_pflat ? pflat : nullptr);
    k_bsum  <<<NBLK, 256, 0, stream>>>(occ, bsum);
    k_scanb <<<1, 1024, 0, stream>>>(bsum);
    k_rank  <<<NBLK, 256, 0, stream>>>(occ, bsum, uniq);
    if (use_pflat)
      k_append<<<nb_pts, 256, 0, stream>>>(pflat, n, occ, cnt, (unsigned*)out);
    else
      k_append_fb<<<nb_pts, 256, 0, stream>>>(pts, n, occ, cnt, (unsigned*)out);
    k_final_d<<<(K + 3) / 4, 256, 0, stream>>>(pts, uniq, cnt, bsum + NBLK, out);
  }
}

// Round 17
// 126.240 us; speedup vs baseline: 1.9391x; 1.9391x over previous
//
#include <hip/hip_runtime.h>

namespace {

constexpr int GX = 400, GY = 400;
constexpr int P = 32;
constexpr int K = 60000;
constexpr int MCAP = 128;
constexpr int NB = 4;
constexpr int NVOX = NB * GX * GY;   // 640000
constexpr int SCAN_CHUNK = 1024;
constexpr int NBLK = (NVOX + 1 + SCAN_CHUNK - 1) / SCAN_CHUNK;  // 626
constexpr int OCC_PAD = NBLK * SCAN_CHUNK;                      // 641024
constexpr int BW2 = 1024;                // flats per bucket
constexpr int NBUK2 = NVOX / BW2;        // 625
constexpr int NBH = 768;                 // padded hist (3 bins/thread in K1)
constexpr int CAPB2 = 14336;             // arena capacity (mean ~10.6k, +36 sigma)
constexpr int PPB = 4096;                // points per K1 block (R17: 2048->4096,
                                         // batch 3.3->6.6 rec = fewer partial lines)
constexpr int IPT = PPB / 256;           // 16 items per thread

constexpr float XMINf = -20.f, YMINf = -20.f, ZMINf = -2.f;
constexpr float XMAXf =  20.f, YMAXf =  20.f, ZMAXf =  3.f;

constexpr int OUT_CNT = K * P * 4;
constexpr int OUT_COR = OUT_CNT + K;

typedef float floatx2 __attribute__((ext_vector_type(2)));

// DO NOT TOUCH: this exact f32 expression matches the np reference's binning.
__device__ __forceinline__ int bin_of(float v) {
  return (int)((v + 20.0f) * 10.0f);
}

__device__ __forceinline__ bool point_voxel(const float* __restrict__ pt, int& flat) {
  float x = pt[1], y = pt[2], z = pt[3];
  bool m = (x >= XMINf) & (x < XMAXf) & (y >= YMINf) & (y < YMAXf)
         & (z >= ZMINf) & (z < ZMAXf);
  if (!m) return false;
  int bi = (int)pt[0];
  int xi = min(max(bin_of(x), 0), GX - 1);
  int yi = min(max(bin_of(y), 0), GY - 1);
  flat = bi * (GX * GY) + xi * GY + yi;
  return true;
}

// ---- pass 1 (fused): read pts, mark occ, LDS-countsort into 625 flat-range
// buckets, flush packed (flat&1023)<<21|idx records to fixed arenas ---------
__global__ void __launch_bounds__(256) k_mark_bucket(
    const float* __restrict__ pts, int n, int* __restrict__ occ,
    int* __restrict__ bcur, unsigned* __restrict__ arena) {
  __shared__ unsigned hist[NBH], lbase[NBH], gbase[NBH], ofs[NBH];
  __shared__ unsigned st[PPB];
  __shared__ unsigned short stb[PPB];
  __shared__ unsigned ps[256];
  __shared__ unsigned tot_s;
  int t = threadIdx.x;
  for (int j = t; j < NBH; j += 256) hist[j] = 0;
  __syncthreads();

  int base = blockIdx.x * PPB;
  int bk[IPT]; unsigned rec[IPT];
  #pragma unroll
  for (int j = 0; j < IPT; ++j) {
    int i = base + j * 256 + t;
    bk[j] = -1;
    if (i < n) {
      int flat;
      if (point_voxel(pts + (size_t)i * 5, flat)) {
        occ[flat] = 1;                          // benign race, plain store
        bk[j] = flat >> 10;
        rec[j] = ((unsigned)(flat & 1023) << 21) | (unsigned)i;
      }
    }
    if (bk[j] >= 0) atomicAdd(&hist[bk[j]], 1u);
  }
  __syncthreads();
  // scan 768 bins, 3 contiguous bins per thread
  unsigned h0 = hist[3 * t], h1 = hist[3 * t + 1], h2 = hist[3 * t + 2];
  unsigned local = h0 + h1 + h2;
  ps[t] = local;
  __syncthreads();
  for (int o = 1; o < 256; o <<= 1) {
    unsigned add = (t >= o) ? ps[t - o] : 0;
    __syncthreads();
    ps[t] += add;
    __syncthreads();
  }
  unsigned excl = ps[t] - local;
  lbase[3 * t] = excl;            ofs[3 * t] = excl;
  lbase[3 * t + 1] = excl + h0;   ofs[3 * t + 1] = excl + h0;
  lbase[3 * t + 2] = excl + h0 + h1; ofs[3 * t + 2] = excl + h0 + h1;
  if (t == 255) tot_s = ps[255];
  __syncthreads();
  #pragma unroll
  for (int j = 0; j < IPT; ++j) {
    if (bk[j] >= 0) {
      unsigned pos = atomicAdd(&ofs[bk[j]], 1u);
      st[pos] = rec[j];
      stb[pos] = (unsigned short)bk[j];
    }
  }
  __syncthreads();
  for (int b = t; b < NBUK2; b += 256) {       // one reservation per bucket
    unsigned nb = hist[b];
    gbase[b] = nb ? (unsigned)atomicAdd(&bcur[b], (int)nb) : 0u;
  }
  __syncthreads();
  unsigned tot = tot_s;
  for (unsigned e = t; e < tot; e += 256) {    // contiguous batch flush
    unsigned b = stb[e];
    unsigned dst = gbase[b] + (e - lbase[b]);
    if (dst < CAPB2) arena[(size_t)b * CAPB2 + dst] = st[e];
  }
}

// ---- pass 2a/2b/2c: occupancy scan chain (proven) ------------------------
__global__ void k_bsum(const int* __restrict__ occ, int* __restrict__ bsum) {
  __shared__ int wsums[4];
  int t = threadIdx.x, wid = t >> 6, lane = t & 63;
  int base = blockIdx.x * SCAN_CHUNK;
  int4 v = ((const int4*)(occ + base))[t];
  int s = v.x + v.y + v.z + v.w;
  for (int o = 32; o > 0; o >>= 1) s += __shfl_xor(s, o, 64);
  if (lane == 0) wsums[wid] = s;
  __syncthreads();
  if (t == 0) bsum[blockIdx.x] = wsums[0] + wsums[1] + wsums[2] + wsums[3];
}

__global__ void k_scanb(int* __restrict__ bsum) {
  __shared__ int lds[1024];
  int t = threadIdx.x;
  int v = (t < NBLK) ? bsum[t] : 0;
  lds[t] = v;
  __syncthreads();
  for (int o = 1; o < 1024; o <<= 1) {
    int add = (t >= o) ? lds[t - o] : 0;
    __syncthreads();
    lds[t] += add;
    __syncthreads();
  }
  if (t < NBLK) bsum[t] = lds[t] - v;
  if (t == NBLK - 1) bsum[NBLK] = lds[t];         // num_unique
}

__global__ void k_rank(int* __restrict__ occ, const int* __restrict__ bsum,
                       int* __restrict__ uniq) {
  __shared__ int wsums[4];
  int t = threadIdx.x, wid = t >> 6, lane = t & 63;
  int base = blockIdx.x * SCAN_CHUNK;
  int4 v = ((const int4*)(occ + base))[t];
  int tsum = v.x + v.y + v.z + v.w;
  int sc = tsum;
  for (int o = 1; o < 64; o <<= 1) {
    int u = __shfl_up(sc, o, 64);
    if (lane >= o) sc += u;
  }
  if (lane == 63) wsums[wid] = sc;
  __syncthreads();
  int woff = 0;
  for (int w = 0; w < wid; ++w) woff += wsums[w];
  int p = bsum[blockIdx.x] + woff + (sc - tsum);
  int e0 = base + t * 4;
  int4 r;
  r.x = p; if (v.x) { if (p < K) uniq[p] = e0 + 0; ++p; }
  r.y = p; if (v.y) { if (p < K) uniq[p] = e0 + 1; ++p; }
  r.z = p; if (v.z) { if (p < K) uniq[p] = e0 + 2; ++p; }
  r.w = p; if (v.w) { if (p < K) uniq[p] = e0 + 3; ++p; }
  ((int4*)(occ + base))[t] = r;
}

// ---- pass 3: per-bucket CSR build IN-PLACE in the arena ------------------
__global__ void __launch_bounds__(256) k_build(
    unsigned* __restrict__ arena, const int* __restrict__ bcur,
    const int* __restrict__ rank, int* __restrict__ voxoff,
    int* __restrict__ vcnt) {
  __shared__ unsigned st[CAPB2];                 // 56 KB
  __shared__ int hist[BW2], scn[BW2], cur[BW2], rk[BW2];
  __shared__ int ps[256];
  int b = blockIdx.x, t = threadIdx.x;
  int tot = min(bcur[b], CAPB2);
  for (int f = t; f < BW2; f += 256) hist[f] = 0;
  __syncthreads();
  unsigned* pb = arena + (size_t)b * CAPB2;
  for (int j = t; j < tot; j += 256) {           // stage + histogram
    unsigned r = pb[j];
    st[j] = r;
    atomicAdd(&hist[r >> 21], 1);
  }
  for (int f = t; f < BW2; f += 256) rk[f] = rank[b * BW2 + f];
  __syncthreads();
  int h0 = hist[4 * t], h1 = hist[4 * t + 1], h2 = hist[4 * t + 2], h3 = hist[4 * t + 3];
  int local = h0 + h1 + h2 + h3;
  ps[t] = local;
  __syncthreads();
  for (int o = 1; o < 256; o <<= 1) {
    int add = (t >= o) ? ps[t - o] : 0;
    __syncthreads();
    ps[t] += add;
    __syncthreads();
  }
  int excl = ps[t] - local;
  scn[4 * t] = excl;                cur[4 * t] = excl;
  scn[4 * t + 1] = excl + h0;       cur[4 * t + 1] = excl + h0;
  scn[4 * t + 2] = excl + h0 + h1;  cur[4 * t + 2] = excl + h0 + h1;
  scn[4 * t + 3] = excl + h0 + h1 + h2; cur[4 * t + 3] = excl + h0 + h1 + h2;
  __syncthreads();
  int cbase = b * CAPB2;
  for (int j = t; j < tot; j += 256) {           // in-place csr scatter
    unsigned r = st[j];
    int slot = atomicAdd(&cur[r >> 21], 1);
    pb[slot] = r & 0x1FFFFFu;
  }
  for (int f = t; f < BW2; f += 256) {
    if (hist[f] > 0) {
      int rr = rk[f];
      if (rr >= 0 && rr < K) { voxoff[rr] = cbase + scn[f]; vcnt[rr] = hist[f]; }
    }
  }
}

// ---- pass 4: contiguous candidate read + bitonic sort + gather + output --
__global__ void __launch_bounds__(256) k_final_csr(
    const float* __restrict__ pts, const unsigned* __restrict__ csr,
    const int* __restrict__ uniq, const int* __restrict__ voxoff,
    const int* __restrict__ vcnt, const int* __restrict__ nuq_p,
    float* __restrict__ out) {
  int wid = threadIdx.x >> 6, lane = threadIdx.x & 63;
  int k = blockIdx.x * 4 + wid;
  if (k >= K) return;
  int nq = min(nuq_p[0], K);
  int c_tot = 0, c_out = 0, s = 0;
  if (k < nq) {
    s = voxoff[k];
    int c = vcnt[k];
    c_tot = min(c, MCAP);
    c_out = min(c, P);
  }
  const unsigned UMAX = 0xffffffffu;
  unsigned v0 = (lane < c_tot) ? csr[s + lane] : UMAX;
  unsigned v1 = (lane + 64 < c_tot) ? csr[s + 64 + lane] : UMAX;

  #pragma unroll
  for (int ph = 1; ph <= 7; ++ph) {
    int kk = 1 << ph;
    bool up = ((lane & (kk >> 1)) == 0);
    #pragma unroll
    for (int d = kk >> 1; d >= 2; d >>= 1) {
      int dl = d >> 1;
      unsigned p0 = __shfl_xor(v0, dl, 64);
      unsigned p1 = __shfl_xor(v1, dl, 64);
      bool low = ((lane & dl) == 0);
      if (low == up) { v0 = min(v0, p0); v1 = min(v1, p1); }
      else           { v0 = max(v0, p0); v1 = max(v1, p1); }
    }
    unsigned lo = min(v0, v1), hi = max(v0, v1);
    v0 = up ? lo : hi;
    v1 = up ? hi : lo;
  }

  int mys = lane >> 1, h = lane & 1;
  unsigned a0 = __shfl(v0, mys >> 1, 64);
  unsigned a1 = __shfl(v1, mys >> 1, 64);
  unsigned myidx = (mys & 1) ? a1 : a0;

  float a = 0.f, b = 0.f;
  if (mys < c_out) {
    const float* pp = pts + (size_t)myidx * 5;
    a = pp[1 + 2 * h];
    b = pp[2 + 2 * h];
  }
  floatx2 val = {a, b};
  __builtin_nontemporal_store(val, (floatx2*)(out + (size_t)k * (P * 4)) + lane);

  if (lane == 0) {
    out[OUT_CNT + k] = (float)c_out;
    int f = (k < nq) ? uniq[k] : NVOX;
    int cb = f / (GX * GY), rem = f % (GX * GY);
    out[OUT_COR + (size_t)k * 3 + 0] = (float)cb;
    out[OUT_COR + (size_t)k * 3 + 1] = (float)(rem / GY);
    out[OUT_COR + (size_t)k * 3 + 2] = (float)(rem % GY);
  }
}

// ======== fallback path C (proven R6): candidates voxel-major in d_out ====
__global__ void k_mark(const float* __restrict__ pts, int n,
                       int* __restrict__ occ, int* __restrict__ pflat) {
  int i = blockIdx.x * blockDim.x + threadIdx.x;
  if (i >= n) return;
  int flat = -1;
  if (point_voxel(pts + (size_t)i * 5, flat)) occ[flat] = 1;
  if (pflat) pflat[i] = flat;
}

__global__ void k_append(const int* __restrict__ pflat, int n,
                         const int* __restrict__ rank, int* __restrict__ cnt,
                         unsigned* __restrict__ vox) {
  int i = blockIdx.x * blockDim.x + threadIdx.x;
  if (i >= n) return;
  int f = pflat[i];
  if (f < 0) return;
  int v = rank[f];
  if (v >= K) return;
  int pos = atomicAdd(&cnt[v], 1);
  if (pos < MCAP) vox[(size_t)v * MCAP + pos] = (unsigned)i;
}

__global__ void k_append_fb(const float* __restrict__ pts, int n,
                            const int* __restrict__ rank, int* __restrict__ cnt,
                            unsigned* __restrict__ vox) {
  int i = blockIdx.x * blockDim.x + threadIdx.x;
  if (i >= n) return;
  int flat;
  if (!point_voxel(pts + (size_t)i * 5, flat)) return;
  int v = rank[flat];
  if (v >= K) return;
  int pos = atomicAdd(&cnt[v], 1);
  if (pos < MCAP) vox[(size_t)v * MCAP + pos] = (unsigned)i;
}

__global__ void __launch_bounds__(256) k_final_d(
    const float* __restrict__ pts, const int* __restrict__ uniq,
    const int* __restrict__ cnt, const int* __restrict__ nuq_p,
    float* __restrict__ out) {
  int wid = threadIdx.x >> 6, lane = threadIdx.x & 63;
  int k = blockIdx.x * 4 + wid;
  if (k >= K) return;
  int nuq = min(nuq_p[0], K);
  int c_tot = 0, c_out = 0;
  if (k < nuq) {
    int c = cnt[k];
    c_tot = min(c, MCAP);
    c_out = min(c, P);
  }
  const unsigned UMAX = 0xffffffffu;
  const unsigned* row = (const unsigned*)out + (size_t)k * MCAP;
  uint2 q = ((const uint2*)row)[lane];
  unsigned v0 = (2 * lane     < c_tot) ? q.x : UMAX;
  unsigned v1 = (2 * lane + 1 < c_tot) ? q.y : UMAX;
  #pragma unroll
  for (int ph = 1; ph <= 7; ++ph) {
    int kk = 1 << ph;
    bool up = ((lane & (kk >> 1)) == 0);
    #pragma unroll
    for (int d = kk >> 1; d >= 2; d >>= 1) {
      int dl = d >> 1;
      unsigned p0 = __shfl_xor(v0, dl, 64);
      unsigned p1 = __shfl_xor(v1, dl, 64);
      bool low = ((lane & dl) == 0);
      if (low == up) { v0 = min(v0, p0); v1 = min(v1, p1); }
      else           { v0 = max(v0, p0); v1 = max(v1, p1); }
    }
    unsigned lo = min(v0, v1), hi = max(v0, v1);
    v0 = up ? lo : hi;
    v1 = up ? hi : lo;
  }
  int mys = lane >> 1, h = lane & 1;
  unsigned a0 = __shfl(v0, mys >> 1, 64);
  unsigned a1 = __shfl(v1, mys >> 1, 64);
  unsigned myidx = (mys & 1) ? a1 : a0;
  float a = 0.f, b = 0.f;
  if (mys < c_out) {
    const float* pp = pts + (size_t)myidx * 5;
    a = pp[1 + 2 * h];
    b = pp[2 + 2 * h];
  }
  float2* vout = (float2*)(out + (size_t)k * (P * 4));
  vout[lane] = make_float2(a, b);
  if (lane == 0) {
    out[OUT_CNT + k] = (float)c_out;
    int f = (k < nuq) ? uniq[k] : NVOX;
    int cb = f / (GX * GY), rem = f % (GX * GY);
    out[OUT_COR + (size_t)k * 3 + 0] = (float)cb;
    out[OUT_COR + (size_t)k * 3 + 1] = (float)(rem / GY);
    out[OUT_COR + (size_t)k * 3 + 2] = (float)(rem % GY);
  }
}

}  // namespace

extern "C" void kernel_launch(void* const* d_in, const int* in_sizes, int n_in,
                              void* d_out, int out_size, void* d_ws, size_t ws_size,
                              hipStream_t stream) {
  const float* pts = (const float*)d_in[0];
  int n = in_sizes[0] / 5;
  float* out = (float*)d_out;
  int nb_pts = (n + 255) / 256;

  // ---- path A layout (ints) ----
  size_t o_occ   = 0;                                // OCC_PAD (becomes rank)
  size_t o_bsum  = o_occ + OCC_PAD;                  // NBLK+1
  size_t o_uniq  = o_bsum + NBLK + 1;                // K
  size_t o_voff  = o_uniq + K;                       // K
  size_t o_vcnt  = o_voff + K;                       // K
  size_t o_bcur  = o_vcnt + K;                       // NBUK2
  size_t o_arena = (o_bcur + NBUK2 + 3) & ~(size_t)3;// NBUK2*CAPB2 (records, then csr in-place)
  size_t totA    = o_arena + (size_t)NBUK2 * CAPB2;

  if (ws_size >= totA * sizeof(int) && n <= (1 << 21)) {
    int* occ   = (int*)d_ws + o_occ;
    int* bsum  = (int*)d_ws + o_bsum;
    int* uniq  = (int*)d_ws + o_uniq;
    int* voff  = (int*)d_ws + o_voff;
    int* vcnt  = (int*)d_ws + o_vcnt;
    int* bcur  = (int*)d_ws + o_bcur;
    unsigned* arena = (unsigned*)((int*)d_ws + o_arena);
    const int* nuq_p = bsum + NBLK;

    hipMemsetAsync(occ, 0, (size_t)OCC_PAD * sizeof(int), stream);
    hipMemsetAsync(bcur, 0, (size_t)NBUK2 * sizeof(int), stream);
    k_mark_bucket<<<(n + PPB - 1) / PPB, 256, 0, stream>>>(pts, n, occ, bcur, arena);
    k_bsum  <<<NBLK, 256, 0, stream>>>(occ, bsum);
    k_scanb <<<1, 1024, 0, stream>>>(bsum);
    k_rank  <<<NBLK, 256, 0, stream>>>(occ, bsum, uniq);
    k_build <<<NBUK2, 256, 0, stream>>>(arena, bcur, occ, voff, vcnt);
    k_final_csr<<<(K + 3) / 4, 256, 0, stream>>>(pts, arena, uniq, voff, vcnt, nuq_p, out);
  } else {
    // ---- path C (R6, proven): candidates voxel-major in d_out ----
    int* occ  = (int*)d_ws;
    int* bsum = occ + OCC_PAD;
    int* uniq = bsum + (NBLK + 1);
    int* cnt  = uniq + K;
    size_t base_ints = (size_t)OCC_PAD + (NBLK + 1) + K + K;
    base_ints = (base_ints + 3) & ~(size_t)3;
    int* pflat = (int*)d_ws + base_ints;
    bool use_pflat = ws_size >= (base_ints + (size_t)n) * sizeof(int);

    hipMemsetAsync(occ, 0, (size_t)OCC_PAD * sizeof(int), stream);
    hipMemsetAsync(cnt, 0, (size_t)K * sizeof(int), stream);
    k_mark  <<<nb_pts, 256, 0, stream>>>(pts, n, occ, use_pflat ? pflat : nullptr);
    k_bsum  <<<NBLK, 256, 0, stream>>>(occ, bsum);
    k_scanb <<<1, 1024, 0, stream>>>(bsum);
    k_rank  <<<NBLK, 256, 0, stream>>>(occ, bsum, uniq);
    if (use_pflat)
      k_append<<<nb_pts, 256, 0, stream>>>(pflat, n, occ, cnt, (unsigned*)out);
    else
      k_append_fb<<<nb_pts, 256, 0, stream>>>(pts, n, occ, cnt, (unsigned*)out);
    k_final_d<<<(K + 3) / 4, 256, 0, stream>>>(pts, uniq, cnt, bsum + NBLK, out);
  }
}